// Round 4
// baseline (454.868 us; speedup 1.0000x reference)
//
#include <hip/hip_runtime.h>
#include <stdint.h>

#define BATCH 16
#define CIN   128
#define HH    56
#define HW    3136      // 56*56
#define NPOS  50176     // 16*3136
#define ECH   768
#define CH1   49        // pos per block for conv1 kernels

// ---------------- static device buffers (no d_ws dependence) ----------------
__device__ uint32_t g_X[NPOS * 8];            // per pos: n[4], s[4] (128 ch)
__device__ uint32_t g_Wp1[ECH * 8];           // per e: n[4], s[4]
__device__ uint32_t g_sw2u[9 * 192];          // dw weights: [tap][dword of 4 ch], int8 signs
__device__ uint32_t g_Wp3[CIN * 48];          // per o: n[24], s[24]
__device__ int8_t   g_bin1[(size_t)NPOS * ECH];
__device__ int8_t   g_z2[(size_t)NPOS * ECH];
__device__ int16_t  g_z3[(size_t)NPOS * CIN]; // layout [n][o][hw] (channel-major)

__device__ int32_t  g_S1[ECH], g_SS1[ECH];
__device__ int32_t  g_S2[ECH], g_SS2[ECH];
__device__ int32_t  g_S3[CIN];
__device__ unsigned long long g_SS3[CIN];
__device__ double   g_Pm[BATCH * CIN];
__device__ double   g_Ys[CIN], g_Yss[CIN];
__device__ float    g_se[BATCH * CIN];

// ternary dot over 128 channels (4 words): a,b in {-1,0,1}
__device__ __forceinline__ int tdot128(const uint32_t* xn, const uint32_t* xsg,
                                       const uint32_t* wn, const uint32_t* wsg) {
  int pc = 0, mc = 0;
#pragma unroll
  for (int k = 0; k < 4; ++k) {
    uint32_t nab = xn[k] & wn[k];
    uint32_t sx  = xsg[k] ^ wsg[k];
    pc += __popc(nab);
    mc += __popc(nab & sx);
  }
  return pc - 2 * mc;
}

// ---------------- K0: pack x (LDS transpose) + weights, zero stats ----------------
// Grid 788: blocks 0..783 pack x (64 positions each); 784..787 do weights/stats.
__global__ __launch_bounds__(256) void k_pack(const float* __restrict__ x,
                                              const float* __restrict__ w1,
                                              const float* __restrict__ w2,
                                              const float* __restrict__ w3) {
  __shared__ uint8_t sh[CIN * 64];   // 8 KB: code per (channel, pos): bit0=nonzero, bit1=sign
  __shared__ uint32_t pk[64 * 8];    // 2 KB: packed output staging
  int b = blockIdx.x, t = threadIdx.x;
  if (b < 784) {
    int pos0 = b * 64;                       // 64 contiguous positions within one image
    int n = pos0 / HW, hw0 = pos0 % HW;
    const float* xp = x + (size_t)n * CIN * HW + hw0;
    int lc = t >> 6, lp = t & 63;
    // phase 1: coalesced load, 4 channels per iteration
#pragma unroll 8
    for (int c4 = 0; c4 < CIN; c4 += 4) {
      float v = xp[(size_t)(c4 + lc) * HW + lp];
      uint8_t code = (v != 0.f) ? (v < 0.f ? 3u : 1u) : 0u;
      sh[(c4 + lc) * 64 + lp] = code;
    }
    __syncthreads();
    // phase 2: each thread packs word w (32 channels) of position p
    int w = t >> 6, p = t & 63;
    uint32_t nw = 0, sw = 0;
#pragma unroll
    for (int i = 0; i < 32; ++i) {
      uint32_t code = sh[(w * 32 + i) * 64 + p];
      nw |= (code & 1u) << i;
      sw |= ((code >> 1) & 1u) << i;
    }
    pk[p * 8 + w] = nw;
    pk[p * 8 + 4 + w] = sw;
    __syncthreads();
    // coalesced store of the 512-dword tile
    uint32_t* dst = g_X + (size_t)b * 512;
    dst[t] = pk[t];
    dst[t + 256] = pk[t + 256];
  } else if (b == 784) {
    for (int e = t; e < ECH; e += 256) {
      const float* wp = w1 + (size_t)e * CIN;
      uint32_t nw[4] = {0,0,0,0}, sw[4] = {0,0,0,0};
      for (int c = 0; c < CIN; ++c) {
        float v = wp[c]; uint32_t bit = 1u << (c & 31);
        if (v != 0.0f) { nw[c >> 5] |= bit; if (v < 0.0f) sw[c >> 5] |= bit; }
      }
      uint32_t* d = g_Wp1 + e * 8;
#pragma unroll
      for (int k = 0; k < 4; ++k) { d[k] = nw[k]; d[4 + k] = sw[k]; }
    }
  } else if (b == 785) {
    if (t < 192) {
      int d = t;
#pragma unroll
      for (int tap = 0; tap < 9; ++tap) {
        uint32_t wd = 0;
#pragma unroll
        for (int bb = 0; bb < 4; ++bb) {
          float v = w2[(size_t)(4 * d + bb) * 9 + tap];
          int s8 = (v > 0.f) - (v < 0.f);
          wd |= ((uint32_t)(uint8_t)(int8_t)s8) << (8 * bb);
        }
        g_sw2u[tap * 192 + d] = wd;
      }
    }
  } else if (b == 786) {
    for (int o = t; o < CIN; o += 256) {
      const float* wp = w3 + (size_t)o * ECH;
      uint32_t nw[24], sw[24];
#pragma unroll
      for (int k = 0; k < 24; ++k) { nw[k] = 0; sw[k] = 0; }
      for (int c = 0; c < ECH; ++c) {
        float v = wp[c]; uint32_t bit = 1u << (c & 31);
        if (v != 0.0f) { nw[c >> 5] |= bit; if (v < 0.0f) sw[c >> 5] |= bit; }
      }
      uint32_t* d = g_Wp3 + o * 48;
#pragma unroll
      for (int k = 0; k < 24; ++k) { d[k] = nw[k]; d[24 + k] = sw[k]; }
    }
  } else { // b == 787: zero stats
    for (int i = t; i < ECH; i += 256) { g_S1[i] = 0; g_SS1[i] = 0; g_S2[i] = 0; g_SS2[i] = 0; }
    if (t < CIN) { g_S3[t] = 0; g_SS3[t] = 0ull; g_Ys[t] = 0.0; g_Yss[t] = 0.0; }
  }
}

// ---------------- K1: conv1 (ternary popcount GEMM) + BN1 stats ----------------
__global__ __launch_bounds__(256) void k_conv1_stats() {
  __shared__ uint32_t xsh[CH1 * 8];
  int b = blockIdx.x, t = threadIdx.x;
  size_t pos0 = (size_t)b * CH1;
  for (int i = t; i < CH1 * 8; i += 256) xsh[i] = g_X[pos0 * 8 + i];
  uint32_t w[3][8];
#pragma unroll
  for (int j = 0; j < 3; ++j) {
    int e = t + j * 256;
#pragma unroll
    for (int k = 0; k < 8; ++k) w[j][k] = g_Wp1[e * 8 + k];
  }
  __syncthreads();
  int s[3] = {0,0,0}, ss[3] = {0,0,0};
  for (int p = 0; p < CH1; ++p) {
    uint32_t xv[8];
#pragma unroll
    for (int k = 0; k < 8; ++k) xv[k] = xsh[p * 8 + k];
#pragma unroll
    for (int j = 0; j < 3; ++j) {
      int z = tdot128(xv, xv + 4, w[j], w[j] + 4);
      s[j] += z; ss[j] += z * z;
    }
  }
#pragma unroll
  for (int j = 0; j < 3; ++j) {
    int e = t + j * 256;
    atomicAdd(&g_S1[e], s[j]); atomicAdd(&g_SS1[e], ss[j]);
  }
}

// ---------------- K2: conv1 recompute + binarize -> bin1 int8 [pos][e] ----------------
__global__ __launch_bounds__(256) void k_conv1_bin(const float* __restrict__ g1,
                                                   const float* __restrict__ b1) {
  __shared__ uint32_t xsh[CH1 * 8];
  int b = blockIdx.x, t = threadIdx.x;
  size_t pos0 = (size_t)b * CH1;
  for (int i = t; i < CH1 * 8; i += 256) xsh[i] = g_X[pos0 * 8 + i];
  uint32_t w[3][8]; float A[3], Bc[3];
#pragma unroll
  for (int j = 0; j < 3; ++j) {
    int e = t + j * 256;
#pragma unroll
    for (int k = 0; k < 8; ++k) w[j][k] = g_Wp1[e * 8 + k];
    double m = (double)g_S1[e] / (double)NPOS;
    double v = (double)g_SS1[e] / (double)NPOS - m * m;
    float inv = (float)(1.0 / sqrt(v + 1e-5));
    A[j] = inv * g1[e]; Bc[j] = b1[e] - (float)m * A[j];
  }
  __syncthreads();
  for (int p = 0; p < CH1; ++p) {
    uint32_t xv[8];
#pragma unroll
    for (int k = 0; k < 8; ++k) xv[k] = xsh[p * 8 + k];
    size_t rowoff = (pos0 + p) * ECH;
#pragma unroll
    for (int j = 0; j < 3; ++j) {
      int z = tdot128(xv, xv + 4, w[j], w[j] + 4);
      float u = fmaf((float)z, A[j], Bc[j]);
      g_bin1[rowoff + t + j * 256] = (int8_t)((u > 0.f) - (u < 0.f));
    }
  }
}

// ---------------- K3: depthwise 3x3 + BN2 stats -> z2 int8 [pos][e] ----------------
// Grid 896 = 16 images x 56 rows. Block 384 = 2 halves (28 output cols each) x 192 dword-chans.
// Rolling 5-column register window, 3 loads per output column, prefetch depth 3.
__global__ __launch_bounds__(384) void k_dw() {
  int b = blockIdx.x, t = threadIdx.x;
  int n = b / HH, h = b % HH;           // uniform per block
  int half = t >= 192 ? 1 : 0;
  int d = t - half * 192;
  int wbeg = half * 28;

  int ws[9][4];
#pragma unroll
  for (int tap = 0; tap < 9; ++tap) {
    uint32_t wd = g_sw2u[tap * 192 + d];
#pragma unroll
    for (int bb = 0; bb < 4; ++bb) ws[tap][bb] = (int)(int8_t)(uint8_t)(wd >> (8 * bb));
  }

  const uint32_t* binu = (const uint32_t*)g_bin1;
  int rowM = (n * HW + h * HH) * 192 + d;       // dword index of (row h, col 0, chan d)
  bool okT = (h > 0), okB = (h < HH - 1);
  int rT = okT ? rowM - HH * 192 : rowM;        // safe clamped row bases
  int rB = okB ? rowM + HH * 192 : rowM;
  uint32_t mT = okT ? 0xffffffffu : 0u;
  uint32_t mB = okB ? 0xffffffffu : 0u;

  uint32_t At, Am, Ab, Bt, Bm, Bb, Ct, Cm, Cb, Dt, Dm, Db, Et, Em, Eb;

#define LOADC(c, vt, vm, vb) do {                                   \
    int cs_ = (c) < 0 ? 0 : ((c) > 55 ? 55 : (c));                  \
    int off_ = cs_ * 192;                                           \
    uint32_t mc_ = ((unsigned)(c) < 56u) ? 0xffffffffu : 0u;        \
    vt = binu[rT + off_];                                           \
    vm = binu[rowM + off_];                                         \
    vb = binu[rB + off_];                                           \
    vt &= (mc_ & mT); vm &= mc_; vb &= (mc_ & mB);                  \
  } while (0)

  LOADC(wbeg - 1, At, Am, Ab);
  LOADC(wbeg,     Bt, Bm, Bb);
  LOADC(wbeg + 1, Ct, Cm, Cb);
  LOADC(wbeg + 2, Dt, Dm, Db);
  LOADC(wbeg + 3, Et, Em, Eb);

  int s0 = 0, s1 = 0, s2 = 0, s3 = 0, q0 = 0, q1 = 0, q2 = 0, q3 = 0;
  uint32_t* z2u = (uint32_t*)g_z2;

#define ACC1(val, tap) do {                                            \
    z0 += __mul24((int)(int8_t)(uint8_t)((val)      ), ws[tap][0]);    \
    z1 += __mul24((int)(int8_t)(uint8_t)((val) >>  8), ws[tap][1]);    \
    z2v+= __mul24((int)(int8_t)(uint8_t)((val) >> 16), ws[tap][2]);    \
    z3 += __mul24((int)(int8_t)(uint8_t)((val) >> 24), ws[tap][3]);    \
  } while (0)

  for (int i = 0; i < 28; ++i) {
    int w = wbeg + i;
    int z0 = 0, z1 = 0, z2v = 0, z3 = 0;
    ACC1(At, 0); ACC1(Bt, 1); ACC1(Ct, 2);
    ACC1(Am, 3); ACC1(Bm, 4); ACC1(Cm, 5);
    ACC1(Ab, 6); ACC1(Bb, 7); ACC1(Cb, 8);
    uint32_t od = (uint32_t)(z0 & 0xff) | ((uint32_t)(z1 & 0xff) << 8) |
                  ((uint32_t)(z2v & 0xff) << 16) | ((uint32_t)(z3 & 0xff) << 24);
    z2u[rowM + w * 192] = od;
    s0 += z0; s1 += z1; s2 += z2v; s3 += z3;
    q0 += __mul24(z0, z0); q1 += __mul24(z1, z1);
    q2 += __mul24(z2v, z2v); q3 += __mul24(z3, z3);
    // shift window, prefetch col w+4
    At = Bt; Am = Bm; Ab = Bb;
    Bt = Ct; Bm = Cm; Bb = Cb;
    Ct = Dt; Cm = Dm; Cb = Db;
    Dt = Et; Dm = Em; Db = Eb;
    LOADC(w + 4, Et, Em, Eb);
  }
#undef LOADC
#undef ACC1

  // block-level stat combine (both halves share channel d)
  __shared__ int shS[ECH], shQ[ECH];
  for (int i = t; i < ECH; i += 384) { shS[i] = 0; shQ[i] = 0; }
  __syncthreads();
  atomicAdd(&shS[4 * d + 0], s0); atomicAdd(&shS[4 * d + 1], s1);
  atomicAdd(&shS[4 * d + 2], s2); atomicAdd(&shS[4 * d + 3], s3);
  atomicAdd(&shQ[4 * d + 0], q0); atomicAdd(&shQ[4 * d + 1], q1);
  atomicAdd(&shQ[4 * d + 2], q2); atomicAdd(&shQ[4 * d + 3], q3);
  __syncthreads();
  for (int i = t; i < ECH; i += 384) {
    atomicAdd(&g_S2[i], shS[i]);
    atomicAdd(&g_SS2[i], shQ[i]);
  }
}

// ---------------- K4: binarize z2 + conv3 popcount GEMM -> z3 i16 [n][o][hw] ----------------
__global__ __launch_bounds__(256) void k_conv3(const float* __restrict__ g2,
                                               const float* __restrict__ b2) {
  __shared__ uint32_t pk[64 * 49];       // 12544 B packed activation bits
  __shared__ float A2s[ECH], B2s[ECH];   // 6144 B
  int b = blockIdx.x, t = threadIdx.x;
  int pos0 = b * 64;
  for (int e = t; e < ECH; e += 256) {
    double m = (double)g_S2[e] / (double)NPOS;
    double v = (double)g_SS2[e] / (double)NPOS - m * m;
    float inv = (float)(1.0 / sqrt(v + 1e-5));
    float Af = inv * g2[e]; A2s[e] = Af; B2s[e] = b2[e] - (float)m * Af;
  }
  __syncthreads();
  int p = t & 63, q = t >> 6;
  // binarize own 192-channel slice of position (pos0+p), read direct from global
  const uint4* src = (const uint4*)(g_z2 + (size_t)(pos0 + p) * ECH + q * 192);
  uint32_t nw[6] = {0,0,0,0,0,0}, sw[6] = {0,0,0,0,0,0};
#pragma unroll
  for (int v = 0; v < 12; ++v) {
    uint4 d4 = src[v];
    uint32_t dws[4] = {d4.x, d4.y, d4.z, d4.w};
#pragma unroll
    for (int dw = 0; dw < 4; ++dw) {
      uint32_t dv = dws[dw];
#pragma unroll
      for (int by = 0; by < 4; ++by) {
        int j = v * 16 + dw * 4 + by;          // channel within q-slice [0,192)
        int c = q * 192 + j;
        float zz = (float)(int)(int8_t)(dv >> (by * 8));
        float u = fmaf(zz, A2s[c], B2s[c]);
        uint32_t bit = 1u << (j & 31);
        if (u != 0.0f) { nw[j >> 5] |= bit; if (u < 0.0f) sw[j >> 5] |= bit; }
      }
    }
  }
#pragma unroll
  for (int k = 0; k < 6; ++k) {
    pk[p * 49 + q * 6 + k] = nw[k];
    pk[p * 49 + 24 + q * 6 + k] = sw[k];
  }
  __syncthreads();
  uint32_t an[24], asx[24];
#pragma unroll
  for (int k = 0; k < 24; ++k) { an[k] = pk[p * 49 + k]; asx[k] = pk[p * 49 + 24 + k]; }
  int n_img = pos0 / HW;
  int hw = pos0 % HW + p;
  for (int i = 0; i < 32; ++i) {
    int o = __builtin_amdgcn_readfirstlane(q * 32 + i);
    const uint32_t* wr = &g_Wp3[o * 48];
    int pc = 0, mc = 0;
#pragma unroll
    for (int k = 0; k < 24; ++k) {
      uint32_t nab = an[k] & wr[k];
      uint32_t sx  = asx[k] ^ wr[24 + k];
      pc += __popc(nab); mc += __popc(nab & sx);
    }
    int z = pc - 2 * mc;
    g_z3[((size_t)n_img * CIN + o) * HW + hw] = (int16_t)z;
  }
}

// ---------------- K4b: BN3 stats from z3 ----------------
__global__ __launch_bounds__(256) void k_stats3() {
  int b = blockIdx.x;            // n*128 + c
  int n = b >> 7, c = b & 127, t = threadIdx.x;
  const uint32_t* zp = (const uint32_t*)(g_z3 + ((size_t)n * CIN + c) * HW);
  int s = 0, ss = 0;
  for (int i = t; i < 1568; i += 256) {
    uint32_t dv = zp[i];
    int a  = (int)(int16_t)(dv & 0xffff);
    int b2 = (int)(int16_t)(dv >> 16);
    s += a + b2; ss += a * a + b2 * b2;
  }
  __shared__ int rs[256], rss[256];
  rs[t] = s; rss[t] = ss; __syncthreads();
  for (int st = 128; st > 0; st >>= 1) {
    if (t < st) { rs[t] += rs[t + st]; rss[t] += rss[t + st]; }
    __syncthreads();
  }
  if (t == 0) {
    atomicAdd(&g_S3[c], rs[0]);
    atomicAdd(&g_SS3[c], (unsigned long long)(unsigned)rss[0]);
  }
}

// ---------------- K5: pooled means of t3 per (n,c) ----------------
__global__ __launch_bounds__(256) void k_pool(const float* __restrict__ g3,
                                              const float* __restrict__ b3) {
  int b = blockIdx.x;        // n*128 + c
  int n = b >> 7, c = b & 127, t = threadIdx.x;
  __shared__ double red[256];
  __shared__ float par[2];
  if (t == 0) {
    double m = (double)g_S3[c] / (double)NPOS;
    double v = (double)g_SS3[c] / (double)NPOS - m * m;
    float inv = (float)(1.0 / sqrt(v + 1e-5));
    float Af = inv * g3[c]; par[0] = Af; par[1] = b3[c] - (float)m * Af;
  }
  __syncthreads();
  float Af = par[0], Bc = par[1];
  const int16_t* zp = g_z3 + ((size_t)n * CIN + c) * HW;
  double acc = 0.0;
  for (int i = t; i < HW; i += 256) {
    float u = fmaf((float)zp[i], Af, Bc);
    u = fminf(1.f, fmaxf(-1.f, u));
    acc += (double)u;
  }
  red[t] = acc; __syncthreads();
  for (int s2 = 128; s2 > 0; s2 >>= 1) { if (t < s2) red[t] += red[t + s2]; __syncthreads(); }
  if (t == 0) g_Pm[b] = red[0];
}

// ---------------- K6: SE path (one block) ----------------
__global__ __launch_bounds__(256) void k_se(const float* __restrict__ g_se1, const float* __restrict__ b_se1,
                                            const float* __restrict__ w_fc2, const float* __restrict__ bias_fc2,
                                            const float* __restrict__ g_se2, const float* __restrict__ b_se2,
                                            const float* __restrict__ w_fc3, const float* __restrict__ bias_fc3,
                                            const float* __restrict__ g_se3, const float* __restrict__ b_se3) {
  __shared__ float s1b[16 * 128];
  __shared__ float s2b[16 * 16];
  __shared__ float zfc[16 * 16];
  int t = threadIdx.x;
  if (t < 128) {
    int c = t; double sum = 0, ssum = 0; double vals[16];
    for (int n = 0; n < 16; ++n) {
      double v = g_Pm[n * 128 + c] / 3136.0;
      vals[n] = v; sum += v; ssum += v * v;
    }
    double m = sum / 16.0, var = ssum / 16.0 - m * m;
    double inv = 1.0 / sqrt(var + 1e-5);
    for (int n = 0; n < 16; ++n) {
      float u = (float)((vals[n] - m) * inv * (double)g_se1[c] + (double)b_se1[c]);
      u = fminf(1.f, fmaxf(-1.f, u));
      s1b[n * 128 + c] = (float)((u > 0.f) - (u < 0.f));
    }
  }
  __syncthreads();
  { // fc2: [16,128] @ bin(w_fc2).T -> [16,16]
    int n = t >> 4, k = t & 15;
    float acc = bias_fc2[k];
    for (int c = 0; c < 128; ++c) {
      float w = w_fc2[k * 128 + c];
      acc += s1b[n * 128 + c] * (float)((w > 0.f) - (w < 0.f));
    }
    zfc[n * 16 + k] = acc;
  }
  __syncthreads();
  if (t < 16) {
    int k = t; double sum = 0, ssum = 0;
    for (int n = 0; n < 16; ++n) { double v = zfc[n * 16 + k]; sum += v; ssum += v * v; }
    double m = sum / 16.0, var = ssum / 16.0 - m * m;
    double inv = 1.0 / sqrt(var + 1e-5);
    for (int n = 0; n < 16; ++n) {
      float u = (float)(((double)zfc[n * 16 + k] - m) * inv * (double)g_se2[k] + (double)b_se2[k]);
      u = fminf(1.f, fmaxf(-1.f, u));
      s2b[n * 16 + k] = (float)((u > 0.f) - (u < 0.f));
    }
  }
  __syncthreads();
  for (int i = t; i < 2048; i += 256) { // fc3: [16,16] @ bin(w_fc3).T -> [16,128]
    int n = i >> 7, c = i & 127;
    float acc = bias_fc3[c];
    for (int k = 0; k < 16; ++k) {
      float w = w_fc3[c * 16 + k];
      acc += s2b[n * 16 + k] * (float)((w > 0.f) - (w < 0.f));
    }
    s1b[i] = acc;  // reuse (fc2 inputs dead)
  }
  __syncthreads();
  if (t < 128) {
    int c = t; double sum = 0, ssum = 0;
    for (int n = 0; n < 16; ++n) { double v = s1b[n * 128 + c]; sum += v; ssum += v * v; }
    double m = sum / 16.0, var = ssum / 16.0 - m * m;
    double inv = 1.0 / sqrt(var + 1e-5);
    for (int n = 0; n < 16; ++n) {
      double u = ((double)s1b[n * 128 + c] - m) * inv * (double)g_se3[c] + (double)b_se3[c];
      g_se[n * 128 + c] = 1.f / (1.f + expf((float)(-u)));
    }
  }
}

// ---------------- K7: stats of y = t3*se + x per channel (final BN) ----------------
__global__ __launch_bounds__(256) void k_ystats(const float* __restrict__ x,
                                                const float* __restrict__ g3,
                                                const float* __restrict__ b3) {
  int b = blockIdx.x;
  int half = b & 1, nc = b >> 1, c = nc & 127, n = nc >> 7;
  int t = threadIdx.x;
  __shared__ double redS[256], redSS[256];
  __shared__ float par[3];
  if (t == 0) {
    double m = (double)g_S3[c] / (double)NPOS;
    double v = (double)g_SS3[c] / (double)NPOS - m * m;
    float inv = (float)(1.0 / sqrt(v + 1e-5));
    float Af = inv * g3[c];
    par[0] = Af; par[1] = b3[c] - (float)m * Af; par[2] = g_se[n * 128 + c];
  }
  __syncthreads();
  float Af = par[0], Bc = par[1], sev = par[2];
  size_t base = ((size_t)n * CIN + c) * HW + half * 1568;
  const int16_t* zp = g_z3 + base;
  const float* xp = x + base;
  double s = 0, ssum = 0;
  for (int i = t; i < 1568; i += 256) {
    float u = fmaf((float)zp[i], Af, Bc);
    u = fminf(1.f, fmaxf(-1.f, u));
    float y = fmaf(u, sev, xp[i]);
    s += (double)y; ssum += (double)y * (double)y;
  }
  redS[t] = s; redSS[t] = ssum; __syncthreads();
  for (int st = 128; st > 0; st >>= 1) {
    if (t < st) { redS[t] += redS[t + st]; redSS[t] += redSS[t + st]; }
    __syncthreads();
  }
  if (t == 0) { atomicAdd(&g_Ys[c], redS[0]); atomicAdd(&g_Yss[c], redSS[0]); }
}

// ---------------- K8: final output ----------------
__global__ __launch_bounds__(256) void k_out(const float* __restrict__ x,
                                             const float* __restrict__ g3,
                                             const float* __restrict__ b3,
                                             const float* __restrict__ gr,
                                             const float* __restrict__ br,
                                             float* __restrict__ out) {
  int b = blockIdx.x;
  int half = b & 1, nc = b >> 1, c = nc & 127, n = nc >> 7;
  int t = threadIdx.x;
  __shared__ float par[5];
  if (t == 0) {
    double m = (double)g_S3[c] / (double)NPOS;
    double v = (double)g_SS3[c] / (double)NPOS - m * m;
    float inv = (float)(1.0 / sqrt(v + 1e-5));
    float A3 = inv * g3[c];
    par[0] = A3; par[1] = b3[c] - (float)m * A3; par[2] = g_se[n * 128 + c];
    double mr = g_Ys[c] / (double)NPOS;
    double vr = g_Yss[c] / (double)NPOS - mr * mr;
    float invr = (float)(1.0 / sqrt(vr + 1e-5));
    float Ar = invr * gr[c];
    par[3] = Ar; par[4] = br[c] - (float)mr * Ar;
  }
  __syncthreads();
  float A3 = par[0], B3 = par[1], sev = par[2], Ar = par[3], Br = par[4];
  size_t base = ((size_t)n * CIN + c) * HW + half * 1568;
  const int16_t* zp = g_z3 + base;
  const float* xp = x + base;
  float* op = out + base;
  for (int i = t; i < 1568; i += 256) {
    float u = fmaf((float)zp[i], A3, B3);
    u = fminf(1.f, fmaxf(-1.f, u));
    float y = fmaf(u, sev, xp[i]);
    float o = fmaf(y, Ar, Br);
    o = fminf(1.f, fmaxf(-1.f, o));
    op[i] = o;
  }
}

// ---------------- launch ----------------
extern "C" void kernel_launch(void* const* d_in, const int* in_sizes, int n_in,
                              void* d_out, int out_size, void* d_ws, size_t ws_size,
                              hipStream_t stream) {
  const float* x       = (const float*)d_in[0];
  const float* w1      = (const float*)d_in[1];
  const float* g1      = (const float*)d_in[2];
  const float* b1      = (const float*)d_in[3];
  const float* w2      = (const float*)d_in[4];
  const float* g2      = (const float*)d_in[5];
  const float* b2      = (const float*)d_in[6];
  const float* w3      = (const float*)d_in[7];
  const float* g3      = (const float*)d_in[8];
  const float* b3      = (const float*)d_in[9];
  const float* g_res   = (const float*)d_in[10];
  const float* b_res   = (const float*)d_in[11];
  const float* g_se1   = (const float*)d_in[12];
  const float* b_se1   = (const float*)d_in[13];
  const float* w_fc2   = (const float*)d_in[14];
  const float* bias_fc2= (const float*)d_in[15];
  const float* g_se2   = (const float*)d_in[16];
  const float* b_se2   = (const float*)d_in[17];
  const float* w_fc3   = (const float*)d_in[18];
  const float* bias_fc3= (const float*)d_in[19];
  const float* g_se3   = (const float*)d_in[20];
  const float* b_se3   = (const float*)d_in[21];
  float* out = (float*)d_out;

  hipLaunchKernelGGL(k_pack,        dim3(788),  dim3(256), 0, stream, x, w1, w2, w3);
  hipLaunchKernelGGL(k_conv1_stats, dim3(1024), dim3(256), 0, stream);
  hipLaunchKernelGGL(k_conv1_bin,   dim3(1024), dim3(256), 0, stream, g1, b1);
  hipLaunchKernelGGL(k_dw,          dim3(896),  dim3(384), 0, stream);
  hipLaunchKernelGGL(k_conv3,       dim3(784),  dim3(256), 0, stream, g2, b2);
  hipLaunchKernelGGL(k_stats3,      dim3(2048), dim3(256), 0, stream);
  hipLaunchKernelGGL(k_pool,        dim3(2048), dim3(256), 0, stream, g3, b3);
  hipLaunchKernelGGL(k_se,          dim3(1),    dim3(256), 0, stream,
                     g_se1, b_se1, w_fc2, bias_fc2, g_se2, b_se2, w_fc3, bias_fc3, g_se3, b_se3);
  hipLaunchKernelGGL(k_ystats,      dim3(4096), dim3(256), 0, stream, x, g3, b3);
  hipLaunchKernelGGL(k_out,         dim3(4096), dim3(256), 0, stream, x, g3, b3, g_res, b_res, out);
}

// Round 5
// 351.830 us; speedup vs baseline: 1.2929x; 1.2929x over previous
//
#include <hip/hip_runtime.h>
#include <stdint.h>

#define BATCH 16
#define CIN   128
#define HH    56
#define HW    3136      // 56*56
#define NPOS  50176     // 16*3136
#define ECH   768
#define CH1   49        // pos per block for conv1 kernels

// ---------------- static device buffers (no d_ws dependence) ----------------
__device__ uint32_t g_X[NPOS * 8];            // per pos: n[4], s[4] (128 ch)
__device__ uint32_t g_Wp1[ECH * 8];           // per e: n[4], s[4]
__device__ uint32_t g_sw2u[9 * 192];          // dw weights: [tap][dword of 4 ch], int8 signs
__device__ uint32_t g_Wp3[CIN * 48];          // per o: n[24], s[24]
__device__ int8_t   g_bin1[(size_t)NPOS * ECH];
__device__ int8_t   g_z2[(size_t)NPOS * ECH];
__device__ int16_t  g_z3[(size_t)NPOS * CIN]; // layout [n][o][hw] (channel-major)

__device__ int32_t  g_S1[ECH], g_SS1[ECH];
__device__ int32_t  g_S2[ECH], g_SS2[ECH];
__device__ int32_t  g_S3[CIN];
__device__ unsigned long long g_SS3[CIN];
__device__ double   g_Pm[BATCH * CIN];
__device__ double   g_Ys[CIN], g_Yss[CIN];
__device__ float    g_se[BATCH * CIN];

// ternary dot over 128 channels (4 words): a,b in {-1,0,1}
__device__ __forceinline__ int tdot128(const uint32_t* xn, const uint32_t* xsg,
                                       const uint32_t* wn, const uint32_t* wsg) {
  int pc = 0, mc = 0;
#pragma unroll
  for (int k = 0; k < 4; ++k) {
    uint32_t nab = xn[k] & wn[k];
    uint32_t sx  = xsg[k] ^ wsg[k];
    pc += __popc(nab);
    mc += __popc(nab & sx);
  }
  return pc - 2 * mc;
}

// ---------------- K0: pack x (LDS transpose) + weights (wave ballot), zero stats ----------------
// Grid 806: blocks 0..783 pack x (64 positions each); 784..795 w1; 796..803 w3; 804 w2; 805 stats.
__global__ __launch_bounds__(256) void k_pack(const float* __restrict__ x,
                                              const float* __restrict__ w1,
                                              const float* __restrict__ w2,
                                              const float* __restrict__ w3) {
  __shared__ uint8_t sh[CIN * 64];   // 8 KB: code per (channel, pos): bit0=nonzero, bit1=sign
  __shared__ uint32_t pk[64 * 8];    // 2 KB: packed output staging
  int b = blockIdx.x, t = threadIdx.x;
  if (b < 784) {
    int pos0 = b * 64;                       // 64 contiguous positions within one image
    int n = pos0 / HW, hw0 = pos0 % HW;
    const float* xp = x + (size_t)n * CIN * HW + hw0;
    int lc = t >> 6, lp = t & 63;
    // phase 1: coalesced load, 4 channels per iteration
#pragma unroll 8
    for (int c4 = 0; c4 < CIN; c4 += 4) {
      float v = xp[(size_t)(c4 + lc) * HW + lp];
      uint8_t code = (v != 0.f) ? (v < 0.f ? 3u : 1u) : 0u;
      sh[(c4 + lc) * 64 + lp] = code;
    }
    __syncthreads();
    // phase 2: each thread packs word w (32 channels) of position p
    int w = t >> 6, p = t & 63;
    uint32_t nw = 0, sw = 0;
#pragma unroll
    for (int i = 0; i < 32; ++i) {
      uint32_t code = sh[(w * 32 + i) * 64 + p];
      nw |= (code & 1u) << i;
      sw |= ((code >> 1) & 1u) << i;
    }
    pk[p * 8 + w] = nw;
    pk[p * 8 + 4 + w] = sw;
    __syncthreads();
    // coalesced store of the 512-dword tile
    uint32_t* dst = g_X + (size_t)b * 512;
    dst[t] = pk[t];
    dst[t + 256] = pk[t + 256];
  } else if (b < 796) {
    // w1 pack: 12 blocks x 4 waves = 48 waves; one wave per row, 2 chunks of 64
    int wid = (b - 784) * 4 + (t >> 6);
    int lane = t & 63;
    for (int e = wid; e < ECH; e += 48) {
      const float* wp = w1 + (size_t)e * CIN;
      float v0 = wp[lane];
      float v1 = wp[64 + lane];
      unsigned long long n0 = __ballot(v0 != 0.f);
      unsigned long long s0 = __ballot(v0 < 0.f);
      unsigned long long n1 = __ballot(v1 != 0.f);
      unsigned long long s1 = __ballot(v1 < 0.f);
      if (lane == 0) {
        uint32_t* d = g_Wp1 + e * 8;
        d[0] = (uint32_t)n0; d[1] = (uint32_t)(n0 >> 32);
        d[2] = (uint32_t)n1; d[3] = (uint32_t)(n1 >> 32);
        d[4] = (uint32_t)s0; d[5] = (uint32_t)(s0 >> 32);
        d[6] = (uint32_t)s1; d[7] = (uint32_t)(s1 >> 32);
      }
    }
  } else if (b < 804) {
    // w3 pack: 8 blocks x 4 waves = 32 waves; one wave per row, 12 chunks of 64
    int wid = (b - 796) * 4 + (t >> 6);
    int lane = t & 63;
    for (int o = wid; o < CIN; o += 32) {
      const float* wp = w3 + (size_t)o * ECH;
      uint32_t* d = g_Wp3 + o * 48;
#pragma unroll
      for (int k = 0; k < 12; ++k) {
        float v = wp[k * 64 + lane];
        unsigned long long nm = __ballot(v != 0.f);
        unsigned long long sm = __ballot(v < 0.f);
        if (lane == 0) {
          d[2 * k]     = (uint32_t)nm; d[2 * k + 1]      = (uint32_t)(nm >> 32);
          d[24 + 2 * k] = (uint32_t)sm; d[24 + 2 * k + 1] = (uint32_t)(sm >> 32);
        }
      }
    }
  } else if (b == 804) {
    if (t < 192) {
      int d = t;
#pragma unroll
      for (int tap = 0; tap < 9; ++tap) {
        uint32_t wd = 0;
#pragma unroll
        for (int bb = 0; bb < 4; ++bb) {
          float v = w2[(size_t)(4 * d + bb) * 9 + tap];
          int s8 = (v > 0.f) - (v < 0.f);
          wd |= ((uint32_t)(uint8_t)(int8_t)s8) << (8 * bb);
        }
        g_sw2u[tap * 192 + d] = wd;
      }
    }
  } else { // b == 805: zero stats
    for (int i = t; i < ECH; i += 256) { g_S1[i] = 0; g_SS1[i] = 0; g_S2[i] = 0; g_SS2[i] = 0; }
    if (t < CIN) { g_S3[t] = 0; g_SS3[t] = 0ull; g_Ys[t] = 0.0; g_Yss[t] = 0.0; }
  }
}

// ---------------- K1: conv1 (ternary popcount GEMM) + BN1 stats ----------------
__global__ __launch_bounds__(256) void k_conv1_stats() {
  __shared__ uint32_t xsh[CH1 * 8];
  int b = blockIdx.x, t = threadIdx.x;
  size_t pos0 = (size_t)b * CH1;
  for (int i = t; i < CH1 * 8; i += 256) xsh[i] = g_X[pos0 * 8 + i];
  uint32_t w[3][8];
#pragma unroll
  for (int j = 0; j < 3; ++j) {
    int e = t + j * 256;
#pragma unroll
    for (int k = 0; k < 8; ++k) w[j][k] = g_Wp1[e * 8 + k];
  }
  __syncthreads();
  int s[3] = {0,0,0}, ss[3] = {0,0,0};
  for (int p = 0; p < CH1; ++p) {
    uint32_t xv[8];
#pragma unroll
    for (int k = 0; k < 8; ++k) xv[k] = xsh[p * 8 + k];
#pragma unroll
    for (int j = 0; j < 3; ++j) {
      int z = tdot128(xv, xv + 4, w[j], w[j] + 4);
      s[j] += z; ss[j] += z * z;
    }
  }
#pragma unroll
  for (int j = 0; j < 3; ++j) {
    int e = t + j * 256;
    atomicAdd(&g_S1[e], s[j]); atomicAdd(&g_SS1[e], ss[j]);
  }
}

// ---------------- K2: conv1 recompute + binarize -> bin1 int8 [pos][e] ----------------
__global__ __launch_bounds__(256) void k_conv1_bin(const float* __restrict__ g1,
                                                   const float* __restrict__ b1) {
  __shared__ uint32_t xsh[CH1 * 8];
  int b = blockIdx.x, t = threadIdx.x;
  size_t pos0 = (size_t)b * CH1;
  for (int i = t; i < CH1 * 8; i += 256) xsh[i] = g_X[pos0 * 8 + i];
  uint32_t w[3][8]; float A[3], Bc[3];
#pragma unroll
  for (int j = 0; j < 3; ++j) {
    int e = t + j * 256;
#pragma unroll
    for (int k = 0; k < 8; ++k) w[j][k] = g_Wp1[e * 8 + k];
    double m = (double)g_S1[e] / (double)NPOS;
    double v = (double)g_SS1[e] / (double)NPOS - m * m;
    float inv = (float)(1.0 / sqrt(v + 1e-5));
    A[j] = inv * g1[e]; Bc[j] = b1[e] - (float)m * A[j];
  }
  __syncthreads();
  for (int p = 0; p < CH1; ++p) {
    uint32_t xv[8];
#pragma unroll
    for (int k = 0; k < 8; ++k) xv[k] = xsh[p * 8 + k];
    size_t rowoff = (pos0 + p) * ECH;
#pragma unroll
    for (int j = 0; j < 3; ++j) {
      int z = tdot128(xv, xv + 4, w[j], w[j] + 4);
      float u = fmaf((float)z, A[j], Bc[j]);
      g_bin1[rowoff + t + j * 256] = (int8_t)((u > 0.f) - (u < 0.f));
    }
  }
}

// ---------------- K3: depthwise 3x3 + BN2 stats -> z2 int8 [pos][e] ----------------
// Grid 896 = 16 images x 56 rows. Block 384 = 2 halves (28 output cols each) x 192 dword-chans.
// Rolling 5-column register window, 3 loads per output column, prefetch depth 3.
__global__ __launch_bounds__(384) void k_dw() {
  int b = blockIdx.x, t = threadIdx.x;
  int n = b / HH, h = b % HH;           // uniform per block
  int half = t >= 192 ? 1 : 0;
  int d = t - half * 192;
  int wbeg = half * 28;

  int ws[9][4];
#pragma unroll
  for (int tap = 0; tap < 9; ++tap) {
    uint32_t wd = g_sw2u[tap * 192 + d];
#pragma unroll
    for (int bb = 0; bb < 4; ++bb) ws[tap][bb] = (int)(int8_t)(uint8_t)(wd >> (8 * bb));
  }

  const uint32_t* binu = (const uint32_t*)g_bin1;
  int rowM = (n * HW + h * HH) * 192 + d;       // dword index of (row h, col 0, chan d)
  bool okT = (h > 0), okB = (h < HH - 1);
  int rT = okT ? rowM - HH * 192 : rowM;        // safe clamped row bases
  int rB = okB ? rowM + HH * 192 : rowM;
  uint32_t mT = okT ? 0xffffffffu : 0u;
  uint32_t mB = okB ? 0xffffffffu : 0u;

  uint32_t At, Am, Ab, Bt, Bm, Bb, Ct, Cm, Cb, Dt, Dm, Db, Et, Em, Eb;

#define LOADC(c, vt, vm, vb) do {                                   \
    int cs_ = (c) < 0 ? 0 : ((c) > 55 ? 55 : (c));                  \
    int off_ = cs_ * 192;                                           \
    uint32_t mc_ = ((unsigned)(c) < 56u) ? 0xffffffffu : 0u;        \
    vt = binu[rT + off_];                                           \
    vm = binu[rowM + off_];                                         \
    vb = binu[rB + off_];                                           \
    vt &= (mc_ & mT); vm &= mc_; vb &= (mc_ & mB);                  \
  } while (0)

  LOADC(wbeg - 1, At, Am, Ab);
  LOADC(wbeg,     Bt, Bm, Bb);
  LOADC(wbeg + 1, Ct, Cm, Cb);
  LOADC(wbeg + 2, Dt, Dm, Db);
  LOADC(wbeg + 3, Et, Em, Eb);

  int s0 = 0, s1 = 0, s2 = 0, s3 = 0, q0 = 0, q1 = 0, q2 = 0, q3 = 0;
  uint32_t* z2u = (uint32_t*)g_z2;

#define ACC1(val, tap) do {                                            \
    z0 += __mul24((int)(int8_t)(uint8_t)((val)      ), ws[tap][0]);    \
    z1 += __mul24((int)(int8_t)(uint8_t)((val) >>  8), ws[tap][1]);    \
    z2v+= __mul24((int)(int8_t)(uint8_t)((val) >> 16), ws[tap][2]);    \
    z3 += __mul24((int)(int8_t)(uint8_t)((val) >> 24), ws[tap][3]);    \
  } while (0)

  for (int i = 0; i < 28; ++i) {
    int w = wbeg + i;
    int z0 = 0, z1 = 0, z2v = 0, z3 = 0;
    ACC1(At, 0); ACC1(Bt, 1); ACC1(Ct, 2);
    ACC1(Am, 3); ACC1(Bm, 4); ACC1(Cm, 5);
    ACC1(Ab, 6); ACC1(Bb, 7); ACC1(Cb, 8);
    uint32_t od = (uint32_t)(z0 & 0xff) | ((uint32_t)(z1 & 0xff) << 8) |
                  ((uint32_t)(z2v & 0xff) << 16) | ((uint32_t)(z3 & 0xff) << 24);
    z2u[rowM + w * 192] = od;
    s0 += z0; s1 += z1; s2 += z2v; s3 += z3;
    q0 += __mul24(z0, z0); q1 += __mul24(z1, z1);
    q2 += __mul24(z2v, z2v); q3 += __mul24(z3, z3);
    // shift window, prefetch col w+4
    At = Bt; Am = Bm; Ab = Bb;
    Bt = Ct; Bm = Cm; Bb = Cb;
    Ct = Dt; Cm = Dm; Cb = Db;
    Dt = Et; Dm = Em; Db = Eb;
    LOADC(w + 4, Et, Em, Eb);
  }
#undef LOADC
#undef ACC1

  // block-level stat combine (both halves share channel d)
  __shared__ int shS[ECH], shQ[ECH];
  for (int i = t; i < ECH; i += 384) { shS[i] = 0; shQ[i] = 0; }
  __syncthreads();
  atomicAdd(&shS[4 * d + 0], s0); atomicAdd(&shS[4 * d + 1], s1);
  atomicAdd(&shS[4 * d + 2], s2); atomicAdd(&shS[4 * d + 3], s3);
  atomicAdd(&shQ[4 * d + 0], q0); atomicAdd(&shQ[4 * d + 1], q1);
  atomicAdd(&shQ[4 * d + 2], q2); atomicAdd(&shQ[4 * d + 3], q3);
  __syncthreads();
  for (int i = t; i < ECH; i += 384) {
    atomicAdd(&g_S2[i], shS[i]);
    atomicAdd(&g_SS2[i], shQ[i]);
  }
}

// ---------------- K4: binarize z2 + conv3 popcount GEMM -> z3 i16 [n][o][hw] ----------------
__global__ __launch_bounds__(256) void k_conv3(const float* __restrict__ g2,
                                               const float* __restrict__ b2) {
  __shared__ uint32_t pk[64 * 49];       // 12544 B packed activation bits
  __shared__ float A2s[ECH], B2s[ECH];   // 6144 B
  int b = blockIdx.x, t = threadIdx.x;
  int pos0 = b * 64;
  for (int e = t; e < ECH; e += 256) {
    double m = (double)g_S2[e] / (double)NPOS;
    double v = (double)g_SS2[e] / (double)NPOS - m * m;
    float inv = (float)(1.0 / sqrt(v + 1e-5));
    float Af = inv * g2[e]; A2s[e] = Af; B2s[e] = b2[e] - (float)m * Af;
  }
  __syncthreads();
  int p = t & 63, q = t >> 6;
  // binarize own 192-channel slice of position (pos0+p), read direct from global
  const uint4* src = (const uint4*)(g_z2 + (size_t)(pos0 + p) * ECH + q * 192);
  uint32_t nw[6] = {0,0,0,0,0,0}, sw[6] = {0,0,0,0,0,0};
#pragma unroll
  for (int v = 0; v < 12; ++v) {
    uint4 d4 = src[v];
    uint32_t dws[4] = {d4.x, d4.y, d4.z, d4.w};
#pragma unroll
    for (int dw = 0; dw < 4; ++dw) {
      uint32_t dv = dws[dw];
#pragma unroll
      for (int by = 0; by < 4; ++by) {
        int j = v * 16 + dw * 4 + by;          // channel within q-slice [0,192)
        int c = q * 192 + j;
        float zz = (float)(int)(int8_t)(dv >> (by * 8));
        float u = fmaf(zz, A2s[c], B2s[c]);
        uint32_t bit = 1u << (j & 31);
        if (u != 0.0f) { nw[j >> 5] |= bit; if (u < 0.0f) sw[j >> 5] |= bit; }
      }
    }
  }
#pragma unroll
  for (int k = 0; k < 6; ++k) {
    pk[p * 49 + q * 6 + k] = nw[k];
    pk[p * 49 + 24 + q * 6 + k] = sw[k];
  }
  __syncthreads();
  uint32_t an[24], asx[24];
#pragma unroll
  for (int k = 0; k < 24; ++k) { an[k] = pk[p * 49 + k]; asx[k] = pk[p * 49 + 24 + k]; }
  int n_img = pos0 / HW;
  int hw = pos0 % HW + p;
  for (int i = 0; i < 32; ++i) {
    int o = __builtin_amdgcn_readfirstlane(q * 32 + i);
    const uint32_t* wr = &g_Wp3[o * 48];
    int pc = 0, mc = 0;
#pragma unroll
    for (int k = 0; k < 24; ++k) {
      uint32_t nab = an[k] & wr[k];
      uint32_t sx  = asx[k] ^ wr[24 + k];
      pc += __popc(nab); mc += __popc(nab & sx);
    }
    int z = pc - 2 * mc;
    g_z3[((size_t)n_img * CIN + o) * HW + hw] = (int16_t)z;
  }
}

// ---------------- K4b: BN3 stats from z3 ----------------
__global__ __launch_bounds__(256) void k_stats3() {
  int b = blockIdx.x;            // n*128 + c
  int n = b >> 7, c = b & 127, t = threadIdx.x;
  const uint32_t* zp = (const uint32_t*)(g_z3 + ((size_t)n * CIN + c) * HW);
  int s = 0, ss = 0;
  for (int i = t; i < 1568; i += 256) {
    uint32_t dv = zp[i];
    int a  = (int)(int16_t)(dv & 0xffff);
    int b2 = (int)(int16_t)(dv >> 16);
    s += a + b2; ss += a * a + b2 * b2;
  }
  __shared__ int rs[256], rss[256];
  rs[t] = s; rss[t] = ss; __syncthreads();
  for (int st = 128; st > 0; st >>= 1) {
    if (t < st) { rs[t] += rs[t + st]; rss[t] += rss[t + st]; }
    __syncthreads();
  }
  if (t == 0) {
    atomicAdd(&g_S3[c], rs[0]);
    atomicAdd(&g_SS3[c], (unsigned long long)(unsigned)rss[0]);
  }
}

// ---------------- K5: pooled means of t3 per (n,c) ----------------
__global__ __launch_bounds__(256) void k_pool(const float* __restrict__ g3,
                                              const float* __restrict__ b3) {
  int b = blockIdx.x;        // n*128 + c
  int n = b >> 7, c = b & 127, t = threadIdx.x;
  __shared__ double red[256];
  __shared__ float par[2];
  if (t == 0) {
    double m = (double)g_S3[c] / (double)NPOS;
    double v = (double)g_SS3[c] / (double)NPOS - m * m;
    float inv = (float)(1.0 / sqrt(v + 1e-5));
    float Af = inv * g3[c]; par[0] = Af; par[1] = b3[c] - (float)m * Af;
  }
  __syncthreads();
  float Af = par[0], Bc = par[1];
  const int16_t* zp = g_z3 + ((size_t)n * CIN + c) * HW;
  double acc = 0.0;
  for (int i = t; i < HW; i += 256) {
    float u = fmaf((float)zp[i], Af, Bc);
    u = fminf(1.f, fmaxf(-1.f, u));
    acc += (double)u;
  }
  red[t] = acc; __syncthreads();
  for (int s2 = 128; s2 > 0; s2 >>= 1) { if (t < s2) red[t] += red[t + s2]; __syncthreads(); }
  if (t == 0) g_Pm[b] = red[0];
}

// ---------------- K6: SE path (one block) ----------------
__global__ __launch_bounds__(256) void k_se(const float* __restrict__ g_se1, const float* __restrict__ b_se1,
                                            const float* __restrict__ w_fc2, const float* __restrict__ bias_fc2,
                                            const float* __restrict__ g_se2, const float* __restrict__ b_se2,
                                            const float* __restrict__ w_fc3, const float* __restrict__ bias_fc3,
                                            const float* __restrict__ g_se3, const float* __restrict__ b_se3) {
  __shared__ float s1b[16 * 128];
  __shared__ float s2b[16 * 16];
  __shared__ float zfc[16 * 16];
  int t = threadIdx.x;
  if (t < 128) {
    int c = t; double sum = 0, ssum = 0; double vals[16];
    for (int n = 0; n < 16; ++n) {
      double v = g_Pm[n * 128 + c] / 3136.0;
      vals[n] = v; sum += v; ssum += v * v;
    }
    double m = sum / 16.0, var = ssum / 16.0 - m * m;
    double inv = 1.0 / sqrt(var + 1e-5);
    for (int n = 0; n < 16; ++n) {
      float u = (float)((vals[n] - m) * inv * (double)g_se1[c] + (double)b_se1[c]);
      u = fminf(1.f, fmaxf(-1.f, u));
      s1b[n * 128 + c] = (float)((u > 0.f) - (u < 0.f));
    }
  }
  __syncthreads();
  { // fc2: [16,128] @ bin(w_fc2).T -> [16,16]
    int n = t >> 4, k = t & 15;
    float acc = bias_fc2[k];
    for (int c = 0; c < 128; ++c) {
      float w = w_fc2[k * 128 + c];
      acc += s1b[n * 128 + c] * (float)((w > 0.f) - (w < 0.f));
    }
    zfc[n * 16 + k] = acc;
  }
  __syncthreads();
  if (t < 16) {
    int k = t; double sum = 0, ssum = 0;
    for (int n = 0; n < 16; ++n) { double v = zfc[n * 16 + k]; sum += v; ssum += v * v; }
    double m = sum / 16.0, var = ssum / 16.0 - m * m;
    double inv = 1.0 / sqrt(var + 1e-5);
    for (int n = 0; n < 16; ++n) {
      float u = (float)(((double)zfc[n * 16 + k] - m) * inv * (double)g_se2[k] + (double)b_se2[k]);
      u = fminf(1.f, fmaxf(-1.f, u));
      s2b[n * 16 + k] = (float)((u > 0.f) - (u < 0.f));
    }
  }
  __syncthreads();
  for (int i = t; i < 2048; i += 256) { // fc3: [16,16] @ bin(w_fc3).T -> [16,128]
    int n = i >> 7, c = i & 127;
    float acc = bias_fc3[c];
    for (int k = 0; k < 16; ++k) {
      float w = w_fc3[c * 16 + k];
      acc += s2b[n * 16 + k] * (float)((w > 0.f) - (w < 0.f));
    }
    s1b[i] = acc;  // reuse (fc2 inputs dead)
  }
  __syncthreads();
  if (t < 128) {
    int c = t; double sum = 0, ssum = 0;
    for (int n = 0; n < 16; ++n) { double v = s1b[n * 128 + c]; sum += v; ssum += v * v; }
    double m = sum / 16.0, var = ssum / 16.0 - m * m;
    double inv = 1.0 / sqrt(var + 1e-5);
    for (int n = 0; n < 16; ++n) {
      double u = ((double)s1b[n * 128 + c] - m) * inv * (double)g_se3[c] + (double)b_se3[c];
      g_se[n * 128 + c] = 1.f / (1.f + expf((float)(-u)));
    }
  }
}

// ---------------- K7: stats of y = t3*se + x per channel (final BN) ----------------
__global__ __launch_bounds__(256) void k_ystats(const float* __restrict__ x,
                                                const float* __restrict__ g3,
                                                const float* __restrict__ b3) {
  int b = blockIdx.x;
  int half = b & 1, nc = b >> 1, c = nc & 127, n = nc >> 7;
  int t = threadIdx.x;
  __shared__ double redS[256], redSS[256];
  __shared__ float par[3];
  if (t == 0) {
    double m = (double)g_S3[c] / (double)NPOS;
    double v = (double)g_SS3[c] / (double)NPOS - m * m;
    float inv = (float)(1.0 / sqrt(v + 1e-5));
    float Af = inv * g3[c];
    par[0] = Af; par[1] = b3[c] - (float)m * Af; par[2] = g_se[n * 128 + c];
  }
  __syncthreads();
  float Af = par[0], Bc = par[1], sev = par[2];
  size_t base = ((size_t)n * CIN + c) * HW + half * 1568;
  const int16_t* zp = g_z3 + base;
  const float* xp = x + base;
  double s = 0, ssum = 0;
  for (int i = t; i < 1568; i += 256) {
    float u = fmaf((float)zp[i], Af, Bc);
    u = fminf(1.f, fmaxf(-1.f, u));
    float y = fmaf(u, sev, xp[i]);
    s += (double)y; ssum += (double)y * (double)y;
  }
  redS[t] = s; redSS[t] = ssum; __syncthreads();
  for (int st = 128; st > 0; st >>= 1) {
    if (t < st) { redS[t] += redS[t + st]; redSS[t] += redSS[t + st]; }
    __syncthreads();
  }
  if (t == 0) { atomicAdd(&g_Ys[c], redS[0]); atomicAdd(&g_Yss[c], redSS[0]); }
}

// ---------------- K8: final output ----------------
__global__ __launch_bounds__(256) void k_out(const float* __restrict__ x,
                                             const float* __restrict__ g3,
                                             const float* __restrict__ b3,
                                             const float* __restrict__ gr,
                                             const float* __restrict__ br,
                                             float* __restrict__ out) {
  int b = blockIdx.x;
  int half = b & 1, nc = b >> 1, c = nc & 127, n = nc >> 7;
  int t = threadIdx.x;
  __shared__ float par[5];
  if (t == 0) {
    double m = (double)g_S3[c] / (double)NPOS;
    double v = (double)g_SS3[c] / (double)NPOS - m * m;
    float inv = (float)(1.0 / sqrt(v + 1e-5));
    float A3 = inv * g3[c];
    par[0] = A3; par[1] = b3[c] - (float)m * A3; par[2] = g_se[n * 128 + c];
    double mr = g_Ys[c] / (double)NPOS;
    double vr = g_Yss[c] / (double)NPOS - mr * mr;
    float invr = (float)(1.0 / sqrt(vr + 1e-5));
    float Ar = invr * gr[c];
    par[3] = Ar; par[4] = br[c] - (float)mr * Ar;
  }
  __syncthreads();
  float A3 = par[0], B3 = par[1], sev = par[2], Ar = par[3], Br = par[4];
  size_t base = ((size_t)n * CIN + c) * HW + half * 1568;
  const int16_t* zp = g_z3 + base;
  const float* xp = x + base;
  float* op = out + base;
  for (int i = t; i < 1568; i += 256) {
    float u = fmaf((float)zp[i], A3, B3);
    u = fminf(1.f, fmaxf(-1.f, u));
    float y = fmaf(u, sev, xp[i]);
    float o = fmaf(y, Ar, Br);
    o = fminf(1.f, fmaxf(-1.f, o));
    op[i] = o;
  }
}

// ---------------- launch ----------------
extern "C" void kernel_launch(void* const* d_in, const int* in_sizes, int n_in,
                              void* d_out, int out_size, void* d_ws, size_t ws_size,
                              hipStream_t stream) {
  const float* x       = (const float*)d_in[0];
  const float* w1      = (const float*)d_in[1];
  const float* g1      = (const float*)d_in[2];
  const float* b1      = (const float*)d_in[3];
  const float* w2      = (const float*)d_in[4];
  const float* g2      = (const float*)d_in[5];
  const float* b2      = (const float*)d_in[6];
  const float* w3      = (const float*)d_in[7];
  const float* g3      = (const float*)d_in[8];
  const float* b3      = (const float*)d_in[9];
  const float* g_res   = (const float*)d_in[10];
  const float* b_res   = (const float*)d_in[11];
  const float* g_se1   = (const float*)d_in[12];
  const float* b_se1   = (const float*)d_in[13];
  const float* w_fc2   = (const float*)d_in[14];
  const float* bias_fc2= (const float*)d_in[15];
  const float* g_se2   = (const float*)d_in[16];
  const float* b_se2   = (const float*)d_in[17];
  const float* w_fc3   = (const float*)d_in[18];
  const float* bias_fc3= (const float*)d_in[19];
  const float* g_se3   = (const float*)d_in[20];
  const float* b_se3   = (const float*)d_in[21];
  float* out = (float*)d_out;

  hipLaunchKernelGGL(k_pack,        dim3(806),  dim3(256), 0, stream, x, w1, w2, w3);
  hipLaunchKernelGGL(k_conv1_stats, dim3(1024), dim3(256), 0, stream);
  hipLaunchKernelGGL(k_conv1_bin,   dim3(1024), dim3(256), 0, stream, g1, b1);
  hipLaunchKernelGGL(k_dw,          dim3(896),  dim3(384), 0, stream);
  hipLaunchKernelGGL(k_conv3,       dim3(784),  dim3(256), 0, stream, g2, b2);
  hipLaunchKernelGGL(k_stats3,      dim3(2048), dim3(256), 0, stream);
  hipLaunchKernelGGL(k_pool,        dim3(2048), dim3(256), 0, stream, g3, b3);
  hipLaunchKernelGGL(k_se,          dim3(1),    dim3(256), 0, stream,
                     g_se1, b_se1, w_fc2, bias_fc2, g_se2, b_se2, w_fc3, bias_fc3, g_se3, b_se3);
  hipLaunchKernelGGL(k_ystats,      dim3(4096), dim3(256), 0, stream, x, g3, b3);
  hipLaunchKernelGGL(k_out,         dim3(4096), dim3(256), 0, stream, x, g3, b3, g_res, b_res, out);
}

// Round 6
// 349.470 us; speedup vs baseline: 1.3016x; 1.0068x over previous
//
#include <hip/hip_runtime.h>
#include <stdint.h>

#define BATCH 16
#define CIN   128
#define HH    56
#define HW    3136      // 56*56
#define NPOS  50176     // 16*3136
#define ECH   768
#define CH1   49        // pos per block for conv1 kernels

// ---------------- static device buffers (no d_ws dependence) ----------------
__device__ uint32_t g_X[NPOS * 8];            // per pos: n[4], s[4] (128 ch)
__device__ uint32_t g_Wp1[ECH * 8];           // per e: n[4], s[4]
__device__ uint32_t g_sw2u[9 * 192];          // dw weights: [tap][dword of 4 ch], int8 signs
__device__ uint32_t g_Wp3[CIN * 48];          // per o: n[24], s[24]
__device__ int8_t   g_bin1[(size_t)NPOS * ECH];
__device__ int8_t   g_z2[(size_t)NPOS * ECH];
__device__ int16_t  g_z3[(size_t)NPOS * CIN]; // layout [n][o][hw] (channel-major)

__device__ int32_t  g_S1[ECH], g_SS1[ECH];
__device__ int32_t  g_S2[ECH], g_SS2[ECH];
__device__ int32_t  g_S3[CIN];
__device__ unsigned long long g_SS3[CIN];
__device__ double   g_Pm[BATCH * CIN];
__device__ double   g_Ys[CIN], g_Yss[CIN];
__device__ float    g_se[BATCH * CIN];

// ternary dot over 128 channels (4 words): a,b in {-1,0,1}
__device__ __forceinline__ int tdot128(const uint32_t* xn, const uint32_t* xsg,
                                       const uint32_t* wn, const uint32_t* wsg) {
  int pc = 0, mc = 0;
#pragma unroll
  for (int k = 0; k < 4; ++k) {
    uint32_t nab = xn[k] & wn[k];
    uint32_t sx  = xsg[k] ^ wsg[k];
    pc += __popc(nab);
    mc += __popc(nab & sx);
  }
  return pc - 2 * mc;
}

// ---------------- K0: pack x (LDS transpose) + weights (wave ballot), zero stats ----------------
// Grid 806: blocks 0..783 pack x (64 positions each); 784..795 w1; 796..803 w3; 804 w2; 805 stats.
__global__ __launch_bounds__(256) void k_pack(const float* __restrict__ x,
                                              const float* __restrict__ w1,
                                              const float* __restrict__ w2,
                                              const float* __restrict__ w3) {
  __shared__ uint8_t sh[CIN * 64];   // 8 KB: code per (channel, pos): bit0=nonzero, bit1=sign
  __shared__ uint32_t pk[64 * 8];    // 2 KB: packed output staging
  int b = blockIdx.x, t = threadIdx.x;
  if (b < 784) {
    int pos0 = b * 64;                       // 64 contiguous positions within one image
    int n = pos0 / HW, hw0 = pos0 % HW;
    const float* xp = x + (size_t)n * CIN * HW + hw0;
    int lc = t >> 6, lp = t & 63;
    // phase 1: coalesced load, 4 channels per iteration
#pragma unroll 8
    for (int c4 = 0; c4 < CIN; c4 += 4) {
      float v = xp[(size_t)(c4 + lc) * HW + lp];
      uint8_t code = (v != 0.f) ? (v < 0.f ? 3u : 1u) : 0u;
      sh[(c4 + lc) * 64 + lp] = code;
    }
    __syncthreads();
    // phase 2: each thread packs word w (32 channels) of position p
    int w = t >> 6, p = t & 63;
    uint32_t nw = 0, sw = 0;
#pragma unroll
    for (int i = 0; i < 32; ++i) {
      uint32_t code = sh[(w * 32 + i) * 64 + p];
      nw |= (code & 1u) << i;
      sw |= ((code >> 1) & 1u) << i;
    }
    pk[p * 8 + w] = nw;
    pk[p * 8 + 4 + w] = sw;
    __syncthreads();
    // coalesced store of the 512-dword tile
    uint32_t* dst = g_X + (size_t)b * 512;
    dst[t] = pk[t];
    dst[t + 256] = pk[t + 256];
  } else if (b < 796) {
    // w1 pack: 12 blocks x 4 waves = 48 waves; one wave per row, 2 chunks of 64
    int wid = (b - 784) * 4 + (t >> 6);
    int lane = t & 63;
    for (int e = wid; e < ECH; e += 48) {
      const float* wp = w1 + (size_t)e * CIN;
      float v0 = wp[lane];
      float v1 = wp[64 + lane];
      unsigned long long n0 = __ballot(v0 != 0.f);
      unsigned long long s0 = __ballot(v0 < 0.f);
      unsigned long long n1 = __ballot(v1 != 0.f);
      unsigned long long s1 = __ballot(v1 < 0.f);
      if (lane == 0) {
        uint32_t* d = g_Wp1 + e * 8;
        d[0] = (uint32_t)n0; d[1] = (uint32_t)(n0 >> 32);
        d[2] = (uint32_t)n1; d[3] = (uint32_t)(n1 >> 32);
        d[4] = (uint32_t)s0; d[5] = (uint32_t)(s0 >> 32);
        d[6] = (uint32_t)s1; d[7] = (uint32_t)(s1 >> 32);
      }
    }
  } else if (b < 804) {
    // w3 pack: 8 blocks x 4 waves = 32 waves; one wave per row, 12 chunks of 64
    int wid = (b - 796) * 4 + (t >> 6);
    int lane = t & 63;
    for (int o = wid; o < CIN; o += 32) {
      const float* wp = w3 + (size_t)o * ECH;
      uint32_t* d = g_Wp3 + o * 48;
#pragma unroll
      for (int k = 0; k < 12; ++k) {
        float v = wp[k * 64 + lane];
        unsigned long long nm = __ballot(v != 0.f);
        unsigned long long sm = __ballot(v < 0.f);
        if (lane == 0) {
          d[2 * k]     = (uint32_t)nm; d[2 * k + 1]      = (uint32_t)(nm >> 32);
          d[24 + 2 * k] = (uint32_t)sm; d[24 + 2 * k + 1] = (uint32_t)(sm >> 32);
        }
      }
    }
  } else if (b == 804) {
    if (t < 192) {
      int d = t;
#pragma unroll
      for (int tap = 0; tap < 9; ++tap) {
        uint32_t wd = 0;
#pragma unroll
        for (int bb = 0; bb < 4; ++bb) {
          float v = w2[(size_t)(4 * d + bb) * 9 + tap];
          int s8 = (v > 0.f) - (v < 0.f);
          wd |= ((uint32_t)(uint8_t)(int8_t)s8) << (8 * bb);
        }
        g_sw2u[tap * 192 + d] = wd;
      }
    }
  } else { // b == 805: zero stats
    for (int i = t; i < ECH; i += 256) { g_S1[i] = 0; g_SS1[i] = 0; g_S2[i] = 0; g_SS2[i] = 0; }
    if (t < CIN) { g_S3[t] = 0; g_SS3[t] = 0ull; g_Ys[t] = 0.0; g_Yss[t] = 0.0; }
  }
}

// ---------------- K1: conv1 (ternary popcount GEMM) + BN1 stats ----------------
__global__ __launch_bounds__(256) void k_conv1_stats() {
  __shared__ uint32_t xsh[CH1 * 8];
  int b = blockIdx.x, t = threadIdx.x;
  size_t pos0 = (size_t)b * CH1;
  for (int i = t; i < CH1 * 8; i += 256) xsh[i] = g_X[pos0 * 8 + i];
  uint32_t w[3][8];
#pragma unroll
  for (int j = 0; j < 3; ++j) {
    int e = t + j * 256;
#pragma unroll
    for (int k = 0; k < 8; ++k) w[j][k] = g_Wp1[e * 8 + k];
  }
  __syncthreads();
  int s[3] = {0,0,0}, ss[3] = {0,0,0};
  for (int p = 0; p < CH1; ++p) {
    uint32_t xv[8];
#pragma unroll
    for (int k = 0; k < 8; ++k) xv[k] = xsh[p * 8 + k];
#pragma unroll
    for (int j = 0; j < 3; ++j) {
      int z = tdot128(xv, xv + 4, w[j], w[j] + 4);
      s[j] += z; ss[j] += z * z;
    }
  }
#pragma unroll
  for (int j = 0; j < 3; ++j) {
    int e = t + j * 256;
    atomicAdd(&g_S1[e], s[j]); atomicAdd(&g_SS1[e], ss[j]);
  }
}

// ---------------- K2: conv1 recompute + binarize -> bin1 int8 [pos][e] ----------------
__global__ __launch_bounds__(256) void k_conv1_bin(const float* __restrict__ g1,
                                                   const float* __restrict__ b1) {
  __shared__ uint32_t xsh[CH1 * 8];
  int b = blockIdx.x, t = threadIdx.x;
  size_t pos0 = (size_t)b * CH1;
  for (int i = t; i < CH1 * 8; i += 256) xsh[i] = g_X[pos0 * 8 + i];
  uint32_t w[3][8]; float A[3], Bc[3];
#pragma unroll
  for (int j = 0; j < 3; ++j) {
    int e = t + j * 256;
#pragma unroll
    for (int k = 0; k < 8; ++k) w[j][k] = g_Wp1[e * 8 + k];
    double m = (double)g_S1[e] / (double)NPOS;
    double v = (double)g_SS1[e] / (double)NPOS - m * m;
    float inv = (float)(1.0 / sqrt(v + 1e-5));
    A[j] = inv * g1[e]; Bc[j] = b1[e] - (float)m * A[j];
  }
  __syncthreads();
  for (int p = 0; p < CH1; ++p) {
    uint32_t xv[8];
#pragma unroll
    for (int k = 0; k < 8; ++k) xv[k] = xsh[p * 8 + k];
    size_t rowoff = (pos0 + p) * ECH;
#pragma unroll
    for (int j = 0; j < 3; ++j) {
      int z = tdot128(xv, xv + 4, w[j], w[j] + 4);
      float u = fmaf((float)z, A[j], Bc[j]);
      g_bin1[rowoff + t + j * 256] = (int8_t)((u > 0.f) - (u < 0.f));
    }
  }
}

// ---------------- K3: depthwise 3x3 + BN2 stats -> z2 int8 [pos][e] ----------------
// Grid 896 = 16 images x 56 rows. Block 384 = 2 halves (28 output cols each) x 192 dword-chans.
// Rolling 5-column register window, 3 loads per output column, prefetch depth 3.
__global__ __launch_bounds__(384) void k_dw() {
  int b = blockIdx.x, t = threadIdx.x;
  int n = b / HH, h = b % HH;           // uniform per block
  int half = t >= 192 ? 1 : 0;
  int d = t - half * 192;
  int wbeg = half * 28;

  int ws[9][4];
#pragma unroll
  for (int tap = 0; tap < 9; ++tap) {
    uint32_t wd = g_sw2u[tap * 192 + d];
#pragma unroll
    for (int bb = 0; bb < 4; ++bb) ws[tap][bb] = (int)(int8_t)(uint8_t)(wd >> (8 * bb));
  }

  const uint32_t* binu = (const uint32_t*)g_bin1;
  int rowM = (n * HW + h * HH) * 192 + d;       // dword index of (row h, col 0, chan d)
  bool okT = (h > 0), okB = (h < HH - 1);
  int rT = okT ? rowM - HH * 192 : rowM;        // safe clamped row bases
  int rB = okB ? rowM + HH * 192 : rowM;
  uint32_t mT = okT ? 0xffffffffu : 0u;
  uint32_t mB = okB ? 0xffffffffu : 0u;

  uint32_t At, Am, Ab, Bt, Bm, Bb, Ct, Cm, Cb, Dt, Dm, Db, Et, Em, Eb;

#define LOADC(c, vt, vm, vb) do {                                   \
    int cs_ = (c) < 0 ? 0 : ((c) > 55 ? 55 : (c));                  \
    int off_ = cs_ * 192;                                           \
    uint32_t mc_ = ((unsigned)(c) < 56u) ? 0xffffffffu : 0u;        \
    vt = binu[rT + off_];                                           \
    vm = binu[rowM + off_];                                         \
    vb = binu[rB + off_];                                           \
    vt &= (mc_ & mT); vm &= mc_; vb &= (mc_ & mB);                  \
  } while (0)

  LOADC(wbeg - 1, At, Am, Ab);
  LOADC(wbeg,     Bt, Bm, Bb);
  LOADC(wbeg + 1, Ct, Cm, Cb);
  LOADC(wbeg + 2, Dt, Dm, Db);
  LOADC(wbeg + 3, Et, Em, Eb);

  int s0 = 0, s1 = 0, s2 = 0, s3 = 0, q0 = 0, q1 = 0, q2 = 0, q3 = 0;
  uint32_t* z2u = (uint32_t*)g_z2;

#define ACC1(val, tap) do {                                            \
    z0 += __mul24((int)(int8_t)(uint8_t)((val)      ), ws[tap][0]);    \
    z1 += __mul24((int)(int8_t)(uint8_t)((val) >>  8), ws[tap][1]);    \
    z2v+= __mul24((int)(int8_t)(uint8_t)((val) >> 16), ws[tap][2]);    \
    z3 += __mul24((int)(int8_t)(uint8_t)((val) >> 24), ws[tap][3]);    \
  } while (0)

  for (int i = 0; i < 28; ++i) {
    int w = wbeg + i;
    int z0 = 0, z1 = 0, z2v = 0, z3 = 0;
    ACC1(At, 0); ACC1(Bt, 1); ACC1(Ct, 2);
    ACC1(Am, 3); ACC1(Bm, 4); ACC1(Cm, 5);
    ACC1(Ab, 6); ACC1(Bb, 7); ACC1(Cb, 8);
    uint32_t od = (uint32_t)(z0 & 0xff) | ((uint32_t)(z1 & 0xff) << 8) |
                  ((uint32_t)(z2v & 0xff) << 16) | ((uint32_t)(z3 & 0xff) << 24);
    z2u[rowM + w * 192] = od;
    s0 += z0; s1 += z1; s2 += z2v; s3 += z3;
    q0 += __mul24(z0, z0); q1 += __mul24(z1, z1);
    q2 += __mul24(z2v, z2v); q3 += __mul24(z3, z3);
    // shift window, prefetch col w+4
    At = Bt; Am = Bm; Ab = Bb;
    Bt = Ct; Bm = Cm; Bb = Cb;
    Ct = Dt; Cm = Dm; Cb = Db;
    Dt = Et; Dm = Em; Db = Eb;
    LOADC(w + 4, Et, Em, Eb);
  }
#undef LOADC
#undef ACC1

  // block-level stat combine (both halves share channel d)
  __shared__ int shS[ECH], shQ[ECH];
  for (int i = t; i < ECH; i += 384) { shS[i] = 0; shQ[i] = 0; }
  __syncthreads();
  atomicAdd(&shS[4 * d + 0], s0); atomicAdd(&shS[4 * d + 1], s1);
  atomicAdd(&shS[4 * d + 2], s2); atomicAdd(&shS[4 * d + 3], s3);
  atomicAdd(&shQ[4 * d + 0], q0); atomicAdd(&shQ[4 * d + 1], q1);
  atomicAdd(&shQ[4 * d + 2], q2); atomicAdd(&shQ[4 * d + 3], q3);
  __syncthreads();
  for (int i = t; i < ECH; i += 384) {
    atomicAdd(&g_S2[i], shS[i]);
    atomicAdd(&g_SS2[i], shQ[i]);
  }
}

// ---------------- K4: binarize z2 + conv3 popcount GEMM -> z3 i16 [n][o][hw] ----------------
// 512 threads = 8 waves: q = t>>6 owns 96 channels (binarize) and 16 outputs (GEMM).
// Grid 784 x 8 waves = 24.5 waves/CU (was 12) — occupancy was the r5 bottleneck.
__global__ __launch_bounds__(512) void k_conv3(const float* __restrict__ g2,
                                               const float* __restrict__ b2) {
  __shared__ uint32_t pk[64 * 49];       // 12544 B packed activation bits
  __shared__ float A2s[ECH], B2s[ECH];   // 6144 B
  int b = blockIdx.x, t = threadIdx.x;
  int pos0 = b * 64;
  for (int e = t; e < ECH; e += 512) {
    double m = (double)g_S2[e] / (double)NPOS;
    double v = (double)g_SS2[e] / (double)NPOS - m * m;
    float inv = (float)(1.0 / sqrt(v + 1e-5));
    float Af = inv * g2[e]; A2s[e] = Af; B2s[e] = b2[e] - (float)m * Af;
  }
  __syncthreads();
  int p = t & 63, q = t >> 6;            // p: position, q: 96-channel / 16-output slice
  // binarize own 96-channel slice of position (pos0+p), read direct from global
  const uint4* src = (const uint4*)(g_z2 + (size_t)(pos0 + p) * ECH + q * 96);
  uint32_t nw[3] = {0,0,0}, sw[3] = {0,0,0};
#pragma unroll
  for (int v = 0; v < 6; ++v) {
    uint4 d4 = src[v];
    uint32_t dws[4] = {d4.x, d4.y, d4.z, d4.w};
#pragma unroll
    for (int dw = 0; dw < 4; ++dw) {
      uint32_t dv = dws[dw];
#pragma unroll
      for (int by = 0; by < 4; ++by) {
        int j = v * 16 + dw * 4 + by;          // channel within q-slice [0,96)
        int c = q * 96 + j;
        float zz = (float)(int)(int8_t)(dv >> (by * 8));
        float u = fmaf(zz, A2s[c], B2s[c]);
        uint32_t bit = 1u << (j & 31);
        if (u != 0.0f) { nw[j >> 5] |= bit; if (u < 0.0f) sw[j >> 5] |= bit; }
      }
    }
  }
#pragma unroll
  for (int k = 0; k < 3; ++k) {
    pk[p * 49 + q * 3 + k] = nw[k];
    pk[p * 49 + 24 + q * 3 + k] = sw[k];
  }
  __syncthreads();
  uint32_t an[24], asx[24];
#pragma unroll
  for (int k = 0; k < 24; ++k) { an[k] = pk[p * 49 + k]; asx[k] = pk[p * 49 + 24 + k]; }
  int n_img = pos0 / HW;
  int hw = pos0 % HW + p;
  for (int i = 0; i < 16; ++i) {
    int o = __builtin_amdgcn_readfirstlane(q * 16 + i);
    const uint32_t* wr = &g_Wp3[o * 48];
    int pc = 0, mc = 0;
#pragma unroll
    for (int k = 0; k < 24; ++k) {
      uint32_t nab = an[k] & wr[k];
      uint32_t sx  = asx[k] ^ wr[24 + k];
      pc += __popc(nab); mc += __popc(nab & sx);
    }
    int z = pc - 2 * mc;
    g_z3[((size_t)n_img * CIN + o) * HW + hw] = (int16_t)z;
  }
}

// ---------------- K4b: BN3 stats from z3 ----------------
__global__ __launch_bounds__(256) void k_stats3() {
  int b = blockIdx.x;            // n*128 + c
  int n = b >> 7, c = b & 127, t = threadIdx.x;
  const uint32_t* zp = (const uint32_t*)(g_z3 + ((size_t)n * CIN + c) * HW);
  int s = 0, ss = 0;
  for (int i = t; i < 1568; i += 256) {
    uint32_t dv = zp[i];
    int a  = (int)(int16_t)(dv & 0xffff);
    int b2 = (int)(int16_t)(dv >> 16);
    s += a + b2; ss += a * a + b2 * b2;
  }
  __shared__ int rs[256], rss[256];
  rs[t] = s; rss[t] = ss; __syncthreads();
  for (int st = 128; st > 0; st >>= 1) {
    if (t < st) { rs[t] += rs[t + st]; rss[t] += rss[t + st]; }
    __syncthreads();
  }
  if (t == 0) {
    atomicAdd(&g_S3[c], rs[0]);
    atomicAdd(&g_SS3[c], (unsigned long long)(unsigned)rss[0]);
  }
}

// ---------------- K5: pooled means of t3 per (n,c) ----------------
__global__ __launch_bounds__(256) void k_pool(const float* __restrict__ g3,
                                              const float* __restrict__ b3) {
  int b = blockIdx.x;        // n*128 + c
  int n = b >> 7, c = b & 127, t = threadIdx.x;
  __shared__ double red[256];
  __shared__ float par[2];
  if (t == 0) {
    double m = (double)g_S3[c] / (double)NPOS;
    double v = (double)g_SS3[c] / (double)NPOS - m * m;
    float inv = (float)(1.0 / sqrt(v + 1e-5));
    float Af = inv * g3[c]; par[0] = Af; par[1] = b3[c] - (float)m * Af;
  }
  __syncthreads();
  float Af = par[0], Bc = par[1];
  const int16_t* zp = g_z3 + ((size_t)n * CIN + c) * HW;
  double acc = 0.0;
  for (int i = t; i < HW; i += 256) {
    float u = fmaf((float)zp[i], Af, Bc);
    u = fminf(1.f, fmaxf(-1.f, u));
    acc += (double)u;
  }
  red[t] = acc; __syncthreads();
  for (int s2 = 128; s2 > 0; s2 >>= 1) { if (t < s2) red[t] += red[t + s2]; __syncthreads(); }
  if (t == 0) g_Pm[b] = red[0];
}

// ---------------- K6: SE path (one block) ----------------
__global__ __launch_bounds__(256) void k_se(const float* __restrict__ g_se1, const float* __restrict__ b_se1,
                                            const float* __restrict__ w_fc2, const float* __restrict__ bias_fc2,
                                            const float* __restrict__ g_se2, const float* __restrict__ b_se2,
                                            const float* __restrict__ w_fc3, const float* __restrict__ bias_fc3,
                                            const float* __restrict__ g_se3, const float* __restrict__ b_se3) {
  __shared__ float s1b[16 * 128];
  __shared__ float s2b[16 * 16];
  __shared__ float zfc[16 * 16];
  int t = threadIdx.x;
  if (t < 128) {
    int c = t; double sum = 0, ssum = 0; double vals[16];
    for (int n = 0; n < 16; ++n) {
      double v = g_Pm[n * 128 + c] / 3136.0;
      vals[n] = v; sum += v; ssum += v * v;
    }
    double m = sum / 16.0, var = ssum / 16.0 - m * m;
    double inv = 1.0 / sqrt(var + 1e-5);
    for (int n = 0; n < 16; ++n) {
      float u = (float)((vals[n] - m) * inv * (double)g_se1[c] + (double)b_se1[c]);
      u = fminf(1.f, fmaxf(-1.f, u));
      s1b[n * 128 + c] = (float)((u > 0.f) - (u < 0.f));
    }
  }
  __syncthreads();
  { // fc2: [16,128] @ bin(w_fc2).T -> [16,16]
    int n = t >> 4, k = t & 15;
    float acc = bias_fc2[k];
    for (int c = 0; c < 128; ++c) {
      float w = w_fc2[k * 128 + c];
      acc += s1b[n * 128 + c] * (float)((w > 0.f) - (w < 0.f));
    }
    zfc[n * 16 + k] = acc;
  }
  __syncthreads();
  if (t < 16) {
    int k = t; double sum = 0, ssum = 0;
    for (int n = 0; n < 16; ++n) { double v = zfc[n * 16 + k]; sum += v; ssum += v * v; }
    double m = sum / 16.0, var = ssum / 16.0 - m * m;
    double inv = 1.0 / sqrt(var + 1e-5);
    for (int n = 0; n < 16; ++n) {
      float u = (float)(((double)zfc[n * 16 + k] - m) * inv * (double)g_se2[k] + (double)b_se2[k]);
      u = fminf(1.f, fmaxf(-1.f, u));
      s2b[n * 16 + k] = (float)((u > 0.f) - (u < 0.f));
    }
  }
  __syncthreads();
  for (int i = t; i < 2048; i += 256) { // fc3: [16,16] @ bin(w_fc3).T -> [16,128]
    int n = i >> 7, c = i & 127;
    float acc = bias_fc3[c];
    for (int k = 0; k < 16; ++k) {
      float w = w_fc3[c * 16 + k];
      acc += s2b[n * 16 + k] * (float)((w > 0.f) - (w < 0.f));
    }
    s1b[i] = acc;  // reuse (fc2 inputs dead)
  }
  __syncthreads();
  if (t < 128) {
    int c = t; double sum = 0, ssum = 0;
    for (int n = 0; n < 16; ++n) { double v = s1b[n * 128 + c]; sum += v; ssum += v * v; }
    double m = sum / 16.0, var = ssum / 16.0 - m * m;
    double inv = 1.0 / sqrt(var + 1e-5);
    for (int n = 0; n < 16; ++n) {
      double u = ((double)s1b[n * 128 + c] - m) * inv * (double)g_se3[c] + (double)b_se3[c];
      g_se[n * 128 + c] = 1.f / (1.f + expf((float)(-u)));
    }
  }
}

// ---------------- K7: stats of y = t3*se + x per channel (final BN) ----------------
__global__ __launch_bounds__(256) void k_ystats(const float* __restrict__ x,
                                                const float* __restrict__ g3,
                                                const float* __restrict__ b3) {
  int b = blockIdx.x;
  int half = b & 1, nc = b >> 1, c = nc & 127, n = nc >> 7;
  int t = threadIdx.x;
  __shared__ double redS[256], redSS[256];
  __shared__ float par[3];
  if (t == 0) {
    double m = (double)g_S3[c] / (double)NPOS;
    double v = (double)g_SS3[c] / (double)NPOS - m * m;
    float inv = (float)(1.0 / sqrt(v + 1e-5));
    float Af = inv * g3[c];
    par[0] = Af; par[1] = b3[c] - (float)m * Af; par[2] = g_se[n * 128 + c];
  }
  __syncthreads();
  float Af = par[0], Bc = par[1], sev = par[2];
  size_t base = ((size_t)n * CIN + c) * HW + half * 1568;
  const int16_t* zp = g_z3 + base;
  const float* xp = x + base;
  double s = 0, ssum = 0;
  for (int i = t; i < 1568; i += 256) {
    float u = fmaf((float)zp[i], Af, Bc);
    u = fminf(1.f, fmaxf(-1.f, u));
    float y = fmaf(u, sev, xp[i]);
    s += (double)y; ssum += (double)y * (double)y;
  }
  redS[t] = s; redSS[t] = ssum; __syncthreads();
  for (int st = 128; st > 0; st >>= 1) {
    if (t < st) { redS[t] += redS[t + st]; redSS[t] += redSS[t + st]; }
    __syncthreads();
  }
  if (t == 0) { atomicAdd(&g_Ys[c], redS[0]); atomicAdd(&g_Yss[c], redSS[0]); }
}

// ---------------- K8: final output ----------------
__global__ __launch_bounds__(256) void k_out(const float* __restrict__ x,
                                             const float* __restrict__ g3,
                                             const float* __restrict__ b3,
                                             const float* __restrict__ gr,
                                             const float* __restrict__ br,
                                             float* __restrict__ out) {
  int b = blockIdx.x;
  int half = b & 1, nc = b >> 1, c = nc & 127, n = nc >> 7;
  int t = threadIdx.x;
  __shared__ float par[5];
  if (t == 0) {
    double m = (double)g_S3[c] / (double)NPOS;
    double v = (double)g_SS3[c] / (double)NPOS - m * m;
    float inv = (float)(1.0 / sqrt(v + 1e-5));
    float A3 = inv * g3[c];
    par[0] = A3; par[1] = b3[c] - (float)m * A3; par[2] = g_se[n * 128 + c];
    double mr = g_Ys[c] / (double)NPOS;
    double vr = g_Yss[c] / (double)NPOS - mr * mr;
    float invr = (float)(1.0 / sqrt(vr + 1e-5));
    float Ar = invr * gr[c];
    par[3] = Ar; par[4] = br[c] - (float)mr * Ar;
  }
  __syncthreads();
  float A3 = par[0], B3 = par[1], sev = par[2], Ar = par[3], Br = par[4];
  size_t base = ((size_t)n * CIN + c) * HW + half * 1568;
  const int16_t* zp = g_z3 + base;
  const float* xp = x + base;
  float* op = out + base;
  for (int i = t; i < 1568; i += 256) {
    float u = fmaf((float)zp[i], A3, B3);
    u = fminf(1.f, fmaxf(-1.f, u));
    float y = fmaf(u, sev, xp[i]);
    float o = fmaf(y, Ar, Br);
    o = fminf(1.f, fmaxf(-1.f, o));
    op[i] = o;
  }
}

// ---------------- launch ----------------
extern "C" void kernel_launch(void* const* d_in, const int* in_sizes, int n_in,
                              void* d_out, int out_size, void* d_ws, size_t ws_size,
                              hipStream_t stream) {
  const float* x       = (const float*)d_in[0];
  const float* w1      = (const float*)d_in[1];
  const float* g1      = (const float*)d_in[2];
  const float* b1      = (const float*)d_in[3];
  const float* w2      = (const float*)d_in[4];
  const float* g2      = (const float*)d_in[5];
  const float* b2      = (const float*)d_in[6];
  const float* w3      = (const float*)d_in[7];
  const float* g3      = (const float*)d_in[8];
  const float* b3      = (const float*)d_in[9];
  const float* g_res   = (const float*)d_in[10];
  const float* b_res   = (const float*)d_in[11];
  const float* g_se1   = (const float*)d_in[12];
  const float* b_se1   = (const float*)d_in[13];
  const float* w_fc2   = (const float*)d_in[14];
  const float* bias_fc2= (const float*)d_in[15];
  const float* g_se2   = (const float*)d_in[16];
  const float* b_se2   = (const float*)d_in[17];
  const float* w_fc3   = (const float*)d_in[18];
  const float* bias_fc3= (const float*)d_in[19];
  const float* g_se3   = (const float*)d_in[20];
  const float* b_se3   = (const float*)d_in[21];
  float* out = (float*)d_out;

  hipLaunchKernelGGL(k_pack,        dim3(806),  dim3(256), 0, stream, x, w1, w2, w3);
  hipLaunchKernelGGL(k_conv1_stats, dim3(1024), dim3(256), 0, stream);
  hipLaunchKernelGGL(k_conv1_bin,   dim3(1024), dim3(256), 0, stream, g1, b1);
  hipLaunchKernelGGL(k_dw,          dim3(896),  dim3(384), 0, stream);
  hipLaunchKernelGGL(k_conv3,       dim3(784),  dim3(512), 0, stream, g2, b2);
  hipLaunchKernelGGL(k_stats3,      dim3(2048), dim3(256), 0, stream);
  hipLaunchKernelGGL(k_pool,        dim3(2048), dim3(256), 0, stream, g3, b3);
  hipLaunchKernelGGL(k_se,          dim3(1),    dim3(256), 0, stream,
                     g_se1, b_se1, w_fc2, bias_fc2, g_se2, b_se2, w_fc3, bias_fc3, g_se3, b_se3);
  hipLaunchKernelGGL(k_ystats,      dim3(4096), dim3(256), 0, stream, x, g3, b3);
  hipLaunchKernelGGL(k_out,         dim3(4096), dim3(256), 0, stream, x, g3, b3, g_res, b_res, out);
}